// Round 2
// baseline (690.301 us; speedup 1.0000x reference)
//
#include <hip/hip_runtime.h>

// DCT-II 2D (ortho) = D @ X @ D^T per 1024x1024 image, 48 images.
// Pipeline: gen D (bf16) -> convert X fp32->bf16 (scratch = front of d_out)
//   -> gemm: Vt = (Xb @ D^T)^T  (bf16, ws)
//   -> gemm: Y  = (Vt @ D^T)^T  (fp32, d_out)
// GEMM: 128x128 tile, BK=64, fragment-major permuted LDS ([g][kc][r] 16B
// chunks) so global_load_lds stays lane-contiguous and ds_read_b128 is
// conflict-free. Transpose is free via mfma operand swap.

typedef __bf16 bf16_t;
typedef __bf16 bf16x8 __attribute__((ext_vector_type(8)));
typedef float  f32x4  __attribute__((ext_vector_type(4)));

#define GLDS16(g, l) \
    __builtin_amdgcn_global_load_lds((__attribute__((address_space(1))) void*)(g), \
                                     (__attribute__((address_space(3))) void*)(l), 16, 0, 0)

// ---- D[k][n] = s_k * cos(pi*(2n+1)*k/2048), exact integer phase mod 4096 ----
__global__ __launch_bounds__(256) void gen_dmat(bf16_t* __restrict__ D) {
    int idx = (blockIdx.x * 256 + threadIdx.x) * 4;
    int k = idx >> 10;
    int n0 = idx & 1023;
    float s = (k == 0) ? 0.03125f : 0.04419417382415922f;  // 1/32, sqrt(2)/32
#pragma unroll
    for (int j = 0; j < 4; ++j) {
        int t = ((2 * (n0 + j) + 1) * k) & 4095;
        D[idx + j] = (bf16_t)(__cosf((float)t * 1.5339807878856412e-3f) * s);
    }
}

// ---- X fp32 -> bf16, 8 elems/thread ----
__global__ __launch_bounds__(256) void conv_bf16(const float* __restrict__ X,
                                                 bf16_t* __restrict__ Xb) {
    size_t i = ((size_t)blockIdx.x * 256 + threadIdx.x) * 8;
    float4 a = *(const float4*)(X + i);
    float4 b = *(const float4*)(X + i + 4);
    bf16x8 o;
    o[0] = (bf16_t)a.x; o[1] = (bf16_t)a.y; o[2] = (bf16_t)a.z; o[3] = (bf16_t)a.w;
    o[4] = (bf16_t)b.x; o[5] = (bf16_t)b.y; o[6] = (bf16_t)b.z; o[7] = (bf16_t)b.w;
    *(bf16x8*)(Xb + i) = o;
}

// ---- Z = transpose(A @ D^T); A bf16 [1024][1024] per batch ----
// LDS tiles stored fragment-major: chunk (g,kc,r) at 16B offset (g*128+kc*16+r)
//   g = row>>4 (0..7), r = row&15, kc = k-chunk of 8 elems (0..7), BK=64.
template <bool OUT_F32>
__global__ __launch_bounds__(256, 3) void dct_gemm(const bf16_t* __restrict__ Ain,
                                                   const bf16_t* __restrict__ Dmat,
                                                   void* __restrict__ Out) {
    __shared__ bf16_t As[8192];   // 16 KB
    __shared__ bf16_t Bs[8192];   // 16 KB

    const int tid  = threadIdx.x;
    const int lane = tid & 63;
    const int wv   = tid >> 6;
    const int l15  = lane & 15;
    const int quad = lane >> 4;

    const int m0 = blockIdx.x * 128;
    const int n0 = blockIdx.y * 128;
    const size_t boff = (size_t)blockIdx.z * 1024 * 1024;

    // staging: 16 GLDS16 per tile; this wave owns s = wv*4 + t, t=0..3
    //   s -> g = s>>1, half = s&1 ; lane -> kc = half*4 + (lane>>4), r = lane&15
    const bf16_t* aSrc[4];
    const bf16_t* bSrc[4];
    int ldsOff[4];
#pragma unroll
    for (int t = 0; t < 4; ++t) {
        int s = wv * 4 + t;
        int g = s >> 1, half = s & 1;
        int row = g * 16 + l15;
        int col = (half * 4 + quad) * 8;
        aSrc[t] = Ain + boff + (size_t)(m0 + row) * 1024 + col;
        bSrc[t] = Dmat + (size_t)(n0 + row) * 1024 + col;
        ldsOff[t] = (g * 128 + half * 64 + lane) * 8;  // uniform base + lane*16B
    }

    f32x4 acc[4][4];
#pragma unroll
    for (int i = 0; i < 4; ++i)
#pragma unroll
        for (int j = 0; j < 4; ++j)
            acc[i][j] = (f32x4){0.f, 0.f, 0.f, 0.f};

    const int ga = (wv & 1) * 4;   // A g-base for this wave (wm/16)
    const int gb = (wv >> 1) * 4;  // B g-base (wn/16)

    for (int k0 = 0; k0 < 1024; k0 += 64) {
        __syncthreads();
#pragma unroll
        for (int t = 0; t < 4; ++t) {
            GLDS16(aSrc[t], &As[ldsOff[t]]);
            GLDS16(bSrc[t], &Bs[ldsOff[t]]);
            aSrc[t] += 64;
            bSrc[t] += 64;
        }
        __syncthreads();

#pragma unroll
        for (int h = 0; h < 2; ++h) {
            bf16x8 af[4], bfr[4];
#pragma unroll
            for (int i = 0; i < 4; ++i)
                af[i] = *(const bf16x8*)&As[(((ga + i) * 8 + h * 4 + quad) * 16 + l15) * 8];
#pragma unroll
            for (int j = 0; j < 4; ++j)
                bfr[j] = *(const bf16x8*)&Bs[(((gb + j) * 8 + h * 4 + quad) * 16 + l15) * 8];
#pragma unroll
            for (int i = 0; i < 4; ++i)
#pragma unroll
                for (int j = 0; j < 4; ++j)
                    acc[i][j] = __builtin_amdgcn_mfma_f32_16x16x32_bf16(bfr[j], af[i], acc[i][j], 0, 0, 0);
        }
    }

    // epilogue: Z[n][m] = C^T in standard C/D layout
    const int wm = (wv & 1) * 64, wn = (wv >> 1) * 64;
    if constexpr (OUT_F32) {
        float* Og = (float*)Out + boff;
#pragma unroll
        for (int j = 0; j < 4; ++j) {
            int zr0 = n0 + wn + j * 16 + quad * 4;
#pragma unroll
            for (int r = 0; r < 4; ++r) {
                float* orow = Og + (size_t)(zr0 + r) * 1024 + m0 + wm + l15;
#pragma unroll
                for (int i = 0; i < 4; ++i)
                    orow[i * 16] = acc[i][j][r];
            }
        }
    } else {
        bf16_t* Og = (bf16_t*)Out + boff;
#pragma unroll
        for (int j = 0; j < 4; ++j) {
            int zr0 = n0 + wn + j * 16 + quad * 4;
#pragma unroll
            for (int r = 0; r < 4; ++r) {
                bf16_t* orow = Og + (size_t)(zr0 + r) * 1024 + m0 + wm + l15;
#pragma unroll
                for (int i = 0; i < 4; ++i)
                    orow[i * 16] = (bf16_t)acc[i][j][r];
            }
        }
    }
}

extern "C" void kernel_launch(void* const* d_in, const int* in_sizes, int n_in,
                              void* d_out, int out_size, void* d_ws, size_t ws_size,
                              hipStream_t stream) {
    (void)in_sizes; (void)n_in; (void)out_size; (void)ws_size;
    const float* X = (const float*)d_in[0];
    float* Y = (float*)d_out;
    const size_t img = (size_t)1024 * 1024;

    // ws: [0,2MB) D bf16 ; [2MB, 2MB+96MB) Vt bf16
    bf16_t* Dm = (bf16_t*)d_ws;
    bf16_t* Vt = (bf16_t*)((char*)d_ws + 2 * img);
    // Xb scratch lives in the front half of d_out (dead until stage-2 rewrite)
    bf16_t* Xb = (bf16_t*)d_out;

    gen_dmat<<<1024, 256, 0, stream>>>(Dm);
    conv_bf16<<<(48 * img) / 2048, 256, 0, stream>>>(X, Xb);

    dim3 grid(8, 8, 48), block(256);
    dct_gemm<false><<<grid, block, 0, stream>>>(Xb, Dm, (void*)Vt);  // Vt = (Xb D^T)^T
    dct_gemm<true ><<<grid, block, 0, stream>>>(Vt, Dm, (void*)Y);   // Y  = (Vt D^T)^T
}